// Round 2
// baseline (488.581 us; speedup 1.0000x reference)
//
#include <hip/hip_runtime.h>
#include <stdint.h>

// Problem constants (fixed by the reference)
#define BQ   2
#define NQ   8192
#define D1Q  128
#define D2Q  256
#define OUTQ 128
#define CATQ 384   // D1+D2
#define KQ   16

// ---------------------------------------------------------------------------
// Kernel 1: transpose W [OUT, CAT] -> Wt [CAT, OUT]  (tiny)
// ---------------------------------------------------------------------------
__global__ void wt_kernel(const float* __restrict__ W, float* __restrict__ Wt) {
    int flat = blockIdx.x * 256 + threadIdx.x;      // k*OUTQ + o
    if (flat < CATQ * OUTQ) {
        int k = flat >> 7;          // / OUTQ
        int o = flat & (OUTQ - 1);
        Wt[flat] = W[o * CATQ + k];
    }
}

// ---------------------------------------------------------------------------
// Kernel 1b: xyz1 norms, bit-exact numpy order:
//   n = (x*x + y*y) + z*z   with each product separately rounded (no FMA).
// Packed as float4 (x,y,z,n) for single ds_read_b128 in the NN kernel.
// ---------------------------------------------------------------------------
__global__ void norm1_kernel(const float* __restrict__ xyz1,
                             float4* __restrict__ xyz1n) {
    int t = blockIdx.x * 256 + threadIdx.x;
    if (t < BQ * NQ) {
        float x = xyz1[t * 3 + 0];
        float y = xyz1[t * 3 + 1];
        float z = xyz1[t * 3 + 2];
        float n;
        {
            #pragma clang fp contract(off)
            float px = x * x, py = y * y, pz = z * z;
            n = (px + py) + pz;
        }
        xyz1n[t] = make_float4(x, y, z, n);
    }
}

// ---------------------------------------------------------------------------
// Kernel 2: projections (unchanged).
//   P1Wb[q][o] = bias[o] + points1[q]·Wt[:,o]   (first 128 rows of Wt)
//   P2W [q][o] =            points2[q]·Wt[128:,o]
// ---------------------------------------------------------------------------
__global__ __launch_bounds__(256) void proj_kernel(
        const float* __restrict__ points1, const float* __restrict__ points2,
        const float* __restrict__ Wt, const float* __restrict__ bias,
        float* __restrict__ P1Wb, float* __restrict__ P2W) {
    __shared__ float p1t[16][D1Q];   // 8 KB
    __shared__ float p2t[16][D2Q];   // 16 KB
    const int tid  = threadIdx.x;
    const int row0 = blockIdx.x * 16;

    {
        const float4* s1 = (const float4*)(points1 + (size_t)row0 * D1Q);
        float4* l1 = (float4*)&p1t[0][0];
        #pragma unroll
        for (int v = tid; v < 16 * D1Q / 4; v += 256) l1[v] = s1[v];
        const float4* s2 = (const float4*)(points2 + (size_t)row0 * D2Q);
        float4* l2 = (float4*)&p2t[0][0];
        #pragma unroll
        for (int v = tid; v < 16 * D2Q / 4; v += 256) l2[v] = s2[v];
    }
    __syncthreads();

    const int o = tid & (OUTQ - 1);
    const int h = tid >> 7;          // 0 or 1 -> rows h*8 .. h*8+7

    float acc[8];
    {
        float bv = bias[o];
        #pragma unroll
        for (int j = 0; j < 8; ++j) acc[j] = bv;
    }
    for (int k = 0; k < D1Q; ++k) {
        float w = Wt[k * OUTQ + o];
        #pragma unroll
        for (int j = 0; j < 8; ++j) acc[j] = fmaf(w, p1t[h * 8 + j][k], acc[j]);
    }
    #pragma unroll
    for (int j = 0; j < 8; ++j)
        P1Wb[(size_t)(row0 + h * 8 + j) * OUTQ + o] = acc[j];

    #pragma unroll
    for (int j = 0; j < 8; ++j) acc[j] = 0.0f;
    for (int k = 0; k < D2Q; ++k) {
        float w = Wt[(D1Q + k) * OUTQ + o];
        #pragma unroll
        for (int j = 0; j < 8; ++j) acc[j] = fmaf(w, p2t[h * 8 + j][k], acc[j]);
    }
    #pragma unroll
    for (int j = 0; j < 8; ++j)
        P2W[(size_t)(row0 + h * 8 + j) * OUTQ + o] = acc[j];
}

// ---------------------------------------------------------------------------
// Kernel 3: fused 16-NN + inverse-distance weights + gather/combine.
// One wave per query; 4 queries per 256-thread block.
//
// d2 replicates numpy's arithmetic bit-for-bit:
//   s2 = (qx*qx + qy*qy) + qz*qz        (separately rounded products)
//   dot = fma(z2,z1, fma(y2,y1, round(x2*x1)))   (BLAS sgemm FMA k-order)
//   d2 = (s2 + s1[n]) - 2*dot           (2*dot exact; two rounded ops)
// Key = (total_order_map(d2 bits) << 32) | idx  -> exact ordering, exact
// index tie-break (top_k stability), full-precision d2 for weights.
// ---------------------------------------------------------------------------
__global__ __launch_bounds__(256) void fpn_kernel(
        const float4* __restrict__ xyz1n, const float* __restrict__ xyz2,
        const float* __restrict__ P1Wb, const float* __restrict__ P2W,
        float* __restrict__ out) {
    // union: tile buffer (16 KB) during NN loop; merge spill (34 KB) after.
    __shared__ __align__(16) char smem[4 * 64 * 17 * 8];   // 34816 B
    float4*   xyzt4 = (float4*)smem;                        // 1024 * 16 B
    uint64_t* mball = (uint64_t*)smem;

    const int tid   = threadIdx.x;
    const int lane  = tid & 63;
    const int w     = tid >> 6;
    const int qflat = blockIdx.x * 4 + w;    // 0..16383
    const int b     = qflat >> 13;           // / NQ

    // query coordinates + norm (wave-uniform), numpy rounding order
    const float* qp = xyz2 + (size_t)qflat * 3;
    const float qx = qp[0], qy = qp[1], qz = qp[2];
    float s2;
    {
        #pragma clang fp contract(off)
        float px = qx * qx, py = qy * qy, pz = qz * qz;
        s2 = (px + py) + pz;
    }

    uint64_t a[16];
    #pragma unroll
    for (int i = 0; i < 16; ++i) a[i] = ~0ull;

    const float4* xb = xyz1n + (size_t)b * NQ;

    for (int tile = 0; tile < 8; ++tile) {
        __syncthreads();   // protect previous tile's readers
        {
            const float4* s4 = xb + tile * 1024;
            #pragma unroll
            for (int v = tid; v < 1024; v += 256) xyzt4[v] = s4[v];
        }
        __syncthreads();

        const uint32_t base = (uint32_t)tile * 1024u;
        #pragma unroll
        for (int s = 0; s < 16; ++s) {
            const int p = s * 64 + lane;
            float4 pt = xyzt4[p];
            float d2;
            {
                #pragma clang fp contract(off)
                float d0  = pt.x * qx;                 // rounded product
                float dot = fmaf(pt.y, qy, d0);        // explicit FMA chain
                dot       = fmaf(pt.z, qz, dot);
                float t   = s2 + pt.w;                 // rounded add
                d2        = t - 2.0f * dot;            // 2*dot exact; rounded sub
            }
            uint32_t bits   = __float_as_uint(d2);
            uint32_t mapped = bits ^ (0x80000000u | (uint32_t)((int32_t)bits >> 31));
            uint64_t key    = ((uint64_t)mapped << 32) | (base + (uint32_t)p);
            if (key < a[15]) {                      // divergent guard
                bool ci = true;                     // c15
                #pragma unroll
                for (int i = 15; i >= 1; --i) {
                    bool cim1 = key < a[i - 1];
                    a[i] = cim1 ? a[i - 1] : (ci ? key : a[i]);
                    ci = cim1;
                }
                a[0] = ci ? key : a[0];
            }
        }
    }

    // smem reuse boundary: all waves must be done reading xyzt4
    __syncthreads();

    // ---- wave-level 64-way sorted-list merge -> global top-16 ----
    uint64_t* mb = mball + ((size_t)w * 64 + lane) * 17;
    #pragma unroll
    for (int i = 0; i < 16; ++i) mb[i] = a[i];
    mb[16] = ~0ull;                          // sentinel

    uint64_t head  = a[0];
    int      ptr   = 0;
    uint64_t mykey = 0;
    #pragma unroll
    for (int r = 0; r < 16; ++r) {
        uint64_t m = head;
        #pragma unroll
        for (int sh = 1; sh < 64; sh <<= 1) {
            uint64_t o2 = __shfl_xor((unsigned long long)m, sh, 64);
            m = (o2 < m) ? o2 : m;
        }
        if (lane == r) mykey = m;
        if (head == m) { ++ptr; head = mb[ptr]; }   // unique keys: one lane advances
    }

    // ---- inverse-distance weights (lanes 0..15 hold the 16 NN) ----
    uint32_t mhi   = (uint32_t)(mykey >> 32);
    uint32_t rbits = (mhi & 0x80000000u) ? (mhi ^ 0x80000000u) : ~mhi;
    float    d2    = __uint_as_float(rbits);
    int      myidx = (int)(uint32_t)(mykey & 0xFFFFFFFFull);
    float recip = (lane < KQ) ? (1.0f / (d2 + 1e-8f)) : 0.0f;
    float tot = recip;
    #pragma unroll
    for (int sh = 1; sh < 64; sh <<= 1) tot += __shfl_xor(tot, sh, 64);
    float wgt = recip / tot;

    // ---- fused gather + combine: out = P1Wb[q] + sum_k w_k * P2W[idx_k] ----
    const float* prow = P1Wb + (size_t)qflat * OUTQ;
    float acc0 = prow[lane];
    float acc1 = prow[lane + 64];
    const float* p2b = P2W + (size_t)b * NQ * OUTQ;
    #pragma unroll
    for (int k = 0; k < KQ; ++k) {
        int   kk = __shfl(myidx, k, 64);
        float wk = __shfl(wgt,   k, 64);
        const float* row = p2b + (size_t)kk * OUTQ;
        acc0 = fmaf(wk, row[lane],      acc0);
        acc1 = fmaf(wk, row[lane + 64], acc1);
    }
    float* orow = out + (size_t)qflat * OUTQ;
    orow[lane]      = acc0;
    orow[lane + 64] = acc1;
}

// ---------------------------------------------------------------------------
// Launch
// ---------------------------------------------------------------------------
extern "C" void kernel_launch(void* const* d_in, const int* in_sizes, int n_in,
                              void* d_out, int out_size, void* d_ws, size_t ws_size,
                              hipStream_t stream) {
    const float* xyz1    = (const float*)d_in[0];
    const float* xyz2    = (const float*)d_in[1];
    const float* points1 = (const float*)d_in[2];
    const float* points2 = (const float*)d_in[3];
    const float* W       = (const float*)d_in[4];
    const float* bias    = (const float*)d_in[5];
    // d_in[6] = nsample (constant 16, compiled in)

    float* wsf  = (float*)d_ws;
    float* Wt   = wsf;                         // 384*128   = 49152 floats
    float* P1Wb = wsf + 49152;                 // 16384*128 = 2097152 floats
    float* P2W  = P1Wb + 2097152;              // 16384*128
    float4* xyz1n = (float4*)(P2W + 2097152);  // 16384 float4 = 65536 floats
    // total ws use ≈ 16.7 MB

    wt_kernel<<<(CATQ * OUTQ + 255) / 256, 256, 0, stream>>>(W, Wt);
    norm1_kernel<<<(BQ * NQ + 255) / 256, 256, 0, stream>>>(xyz1, xyz1n);
    proj_kernel<<<(BQ * NQ) / 16, 256, 0, stream>>>(points1, points2, Wt, bias, P1Wb, P2W);
    fpn_kernel<<<(BQ * NQ) / 4, 256, 0, stream>>>(xyz1n, xyz2, P1Wb, P2W, (float*)d_out);
}